// Round 1
// baseline (2436.111 us; speedup 1.0000x reference)
//
#include <hip/hip_runtime.h>

#define HID   64
#define SEQT  1024

__device__ __forceinline__ float rcpf(float x) { return __builtin_amdgcn_rcpf(x); }
__device__ __forceinline__ float sigm(float x) { return rcpf(1.0f + __expf(-x)); }
__device__ __forceinline__ float tanh_fast(float x) {
    // 1 - 2/(e^{2x}+1); saturates correctly for |x| large (inf -> 1, 0 -> -1)
    return 1.0f - 2.0f * rcpf(__expf(2.0f * x) + 1.0f);
}

// One block = one batch element. 4 waves; wave w owns gate type w (i,f,g,o),
// lane j owns gate g = 64*w + j of BOTH layers. Weights register-resident
// (192 VGPRs/lane). h state broadcast via per-wave LDS copies (float4
// same-address broadcast reads = conflict-free). 2 barriers per timestep.
__global__ __launch_bounds__(256, 2)
void lstm2_fused(const float* __restrict__ x,
                 const float* __restrict__ W_ih0, const float* __restrict__ W_hh0,
                 const float* __restrict__ b_ih0, const float* __restrict__ b_hh0,
                 const float* __restrict__ W_ih1, const float* __restrict__ W_hh1,
                 const float* __restrict__ b_ih1, const float* __restrict__ b_hh1,
                 const float* __restrict__ fc1_w, const float* __restrict__ fc1_b,
                 const float* __restrict__ fc2_w, const float* __restrict__ fc2_b,
                 float* __restrict__ out, int batch)
{
    const int b   = blockIdx.x;
    if (b >= batch) return;
    const int tid = threadIdx.x;
    const int w   = tid >> 6;     // wave = gate type
    const int j   = tid & 63;     // lane = unit index for updates
    const int g   = tid;          // gate index 0..255

    __shared__ float gates0[256];
    __shared__ float gates1[256];
    __shared__ __align__(16) float h1buf[4][HID];  // per-wave replicated h1
    __shared__ __align__(16) float h2buf[4][HID];  // per-wave replicated h2

    // ---- preload this lane's weight rows into registers ----
    float whh0[HID], wih1[HID], whh1[HID];
    #pragma unroll
    for (int k = 0; k < HID; ++k) {
        whh0[k] = W_hh0[g * HID + k];
        wih1[k] = W_ih1[g * HID + k];
        whh1[k] = W_hh1[g * HID + k];
    }
    const float wih0g = W_ih0[g];               // INPUT_SIZE == 1
    const float bias0 = b_ih0[g] + b_hh0[g];
    const float bias1 = b_ih1[g] + b_hh1[g];

    float c1 = 0.0f, c2 = 0.0f;
    h1buf[w][j] = 0.0f;
    h2buf[w][j] = 0.0f;
    __syncthreads();

    const float* __restrict__ xrow = x + (size_t)b * SEQT;
    float* __restrict__ h1w = h1buf[w];
    float* __restrict__ h2w = h2buf[w];
    const float4* __restrict__ h1v4 = (const float4*)h1w;
    const float4* __restrict__ h2v4 = (const float4*)h2w;

    for (int t0 = 0; t0 < SEQT; t0 += 64) {
        const float xchunk = xrow[t0 + j];      // 64 future timesteps, one per lane
        #pragma unroll 1
        for (int tt = 0; tt < 64; ++tt) {
            const float xt = __shfl(xchunk, tt);

            // ---------- layer 0: gate g = x_t*Wih0[g] + h1 . Whh0[g] ----------
            float a0 = 0.f, a1 = 0.f, a2 = 0.f, a3 = 0.f;
            #pragma unroll
            for (int q = 0; q < 16; ++q) {
                float4 h4 = h1v4[q];            // broadcast ds_read_b128
                a0 = fmaf(h4.x, whh0[4*q+0], a0);
                a1 = fmaf(h4.y, whh0[4*q+1], a1);
                a2 = fmaf(h4.z, whh0[4*q+2], a2);
                a3 = fmaf(h4.w, whh0[4*q+3], a3);
            }
            float pre0 = fmaf(xt, wih0g, bias0) + ((a0 + a1) + (a2 + a3));
            float act0 = (w == 2) ? tanh_fast(pre0) : sigm(pre0);  // wave-uniform branch
            gates0[g] = act0;
            __syncthreads();

            // ---------- layer 0 cell update, unit j (redundant per wave) ------
            float i0 = gates0[j];
            float f0 = gates0[64 + j];
            float g0 = gates0[128 + j];
            float o0 = gates0[192 + j];
            c1 = fmaf(f0, c1, i0 * g0);
            float h1n = o0 * tanh_fast(c1);
            h1w[j] = h1n;                        // own-wave copy, no barrier needed

            // ---------- layer 1: gate g = h1_t . Wih1[g] + h2 . Whh1[g] -------
            float s0 = 0.f, s1 = 0.f, s2 = 0.f, s3 = 0.f;
            #pragma unroll
            for (int q = 0; q < 16; ++q) {
                float4 u = h1v4[q];
                float4 v = h2v4[q];
                s0 = fmaf(u.x, wih1[4*q+0], s0);
                s1 = fmaf(u.y, wih1[4*q+1], s1);
                s2 = fmaf(u.z, wih1[4*q+2], s2);
                s3 = fmaf(u.w, wih1[4*q+3], s3);
                s0 = fmaf(v.x, whh1[4*q+0], s0);
                s1 = fmaf(v.y, whh1[4*q+1], s1);
                s2 = fmaf(v.z, whh1[4*q+2], s2);
                s3 = fmaf(v.w, whh1[4*q+3], s3);
            }
            float pre1 = bias1 + ((s0 + s1) + (s2 + s3));
            float act1 = (w == 2) ? tanh_fast(pre1) : sigm(pre1);
            gates1[g] = act1;
            __syncthreads();

            // ---------- layer 1 cell update --------------------------------
            float i1 = gates1[j];
            float f1 = gates1[64 + j];
            float g1 = gates1[128 + j];
            float o1 = gates1[192 + j];
            c2 = fmaf(f1, c2, i1 * g1);
            float h2n = o1 * tanh_fast(c2);
            h2w[j] = h2n;
        }
    }

    // ---------- FC head: out[b] = fc2( relu( fc1(h2_last) ) ) ----------
    if (w == 0) {
        float z = 0.0f;
        if (j < 32) {
            float acc = fc1_b[j];
            #pragma unroll
            for (int k = 0; k < HID; ++k)
                acc = fmaf(h2w[k], fc1_w[j * HID + k], acc);
            z = fmaxf(acc, 0.0f) * fc2_w[j];
        }
        #pragma unroll
        for (int off = 32; off > 0; off >>= 1)
            z += __shfl_xor(z, off);
        if (j == 0) out[b] = z + fc2_b[0];
    }
}

extern "C" void kernel_launch(void* const* d_in, const int* in_sizes, int n_in,
                              void* d_out, int out_size, void* d_ws, size_t ws_size,
                              hipStream_t stream) {
    const float* x     = (const float*)d_in[0];
    const float* W_ih0 = (const float*)d_in[1];
    const float* W_hh0 = (const float*)d_in[2];
    const float* b_ih0 = (const float*)d_in[3];
    const float* b_hh0 = (const float*)d_in[4];
    const float* W_ih1 = (const float*)d_in[5];
    const float* W_hh1 = (const float*)d_in[6];
    const float* b_ih1 = (const float*)d_in[7];
    const float* b_hh1 = (const float*)d_in[8];
    const float* fc1_w = (const float*)d_in[9];
    const float* fc1_b = (const float*)d_in[10];
    const float* fc2_w = (const float*)d_in[11];
    const float* fc2_b = (const float*)d_in[12];
    float* out = (float*)d_out;

    const int batch = in_sizes[0] / SEQT;   // 1024
    dim3 grid(batch), block(256);
    hipLaunchKernelGGL(lstm2_fused, grid, block, 0, stream,
                       x, W_ih0, W_hh0, b_ih0, b_hh0,
                       W_ih1, W_hh1, b_ih1, b_hh1,
                       fc1_w, fc1_b, fc2_w, fc2_b, out, batch);
}